// Round 15
// baseline (73.848 us; speedup 1.0000x reference)
//
#include <hip/hip_runtime.h>
#include <math.h>
#include <stdint.h>

#define NN 8192
#define DD 1024
#define KT 2048   // 2*D
#define HH 100
#define HP 128    // padded hidden
#define LCAP 512
#define NB 32

typedef short bf16x8 __attribute__((ext_vector_type(8)));
typedef float f32x4 __attribute__((ext_vector_type(4)));
typedef const __attribute__((address_space(1))) char GC;
typedef __attribute__((address_space(3))) char LC;

__device__ __forceinline__ short f2bf(float f) {
    uint32_t u = __builtin_bit_cast(uint32_t, f);
    u += 0x7FFF + ((u >> 16) & 1);   // RTNE
    return (short)(u >> 16);
}

// W1 fp32 [2048][100] -> w1p packed fragments (verified R9-R13):
// w1p[((c32*8 + tile)*64 + lane)*8 + j] = bf16(W1[c32*32 + (lane>>4)*8 + j][tile*16 + (lane&15)])
// Block 0 zeroes compaction counters.
__global__ __launch_bounds__(256) void prep_w1p(const float* __restrict__ W1,
                                                short* __restrict__ w1p,
                                                int* __restrict__ cnt1,
                                                int* __restrict__ cnt0)
{
    __shared__ float ld[32][104];
    const int t  = threadIdx.x;
    if (blockIdx.x == 0 && t < 64) {
        if (t < 32) cnt1[t] = 0; else cnt0[t - 32] = 0;
    }
    const int k0 = blockIdx.x * 32;          // 64 blocks
    for (int i = t; i < 32 * HH; i += 256) {
        const int kk = i / HH, cc = i - kk * HH;
        ld[kk][cc] = W1[(size_t)(k0 + kk) * HH + cc];
    }
    __syncthreads();
    for (int idx = t; idx < 512; idx += 256) {
        const int tt = idx >> 6, l = idx & 63;
        const int lr = l & 15, lg = l >> 4;
        const int col = tt * 16 + lr;
        bf16x8 r;
#pragma unroll
        for (int j = 0; j < 8; ++j)
            r[j] = (col < HH) ? f2bf(ld[lg * 8 + j][col]) : (short)0;
        *(bf16x8*)(w1p + ((size_t)(blockIdx.x * 8 + tt) * 64 + l) * 8) = r;
    }
}

// 512 thr / 8 waves; 16 rows/block; 512 blocks (XCD-swizzled), 1 block/CU.
// A: FULL K staged fp32 via global_load_lds width-16 (async DMA, no VGPR trip),
// source pre-swizzled so ds_read_b128 fragment reads are conflict-free (m173).
// Wave w owns col tile w (16 cols). Barrier-free 64-body K-loop; B from packed
// w1p in 4-deep register batches (static-indexed).
__global__ __launch_bounds__(512) void encoder_mfma(
    const float* __restrict__ q, const float* __restrict__ x,
    const short* __restrict__ w1p,
    const float* __restrict__ b1, const float* __restrict__ W2,
    const float* __restrict__ b2,
    const int* __restrict__ bidx, const int* __restrict__ y,
    float* __restrict__ sp, float* __restrict__ sn,
    int* __restrict__ cnt1, int* __restrict__ cnt0)
{
    __shared__ float As[16][KT];        // 128 KB, 16B-unit XOR swizzle per row
    __shared__ float hsum[16][HP + 8];  // 136: 16B-aligned rows
    const int t  = threadIdx.x;
    const int w  = t >> 6;              // wave 0..7 = col tile
    const int l  = t & 63;
    const int lr = l & 15;
    const int lg = l >> 4;
    const int hw = blockIdx.x;
    const int bid = (hw & 7) * 64 + (hw >> 3);   // XCD chunk swizzle (512 = 8*64)
    const int r0 = bid * 16;

    // ---- stage 16 rows x 2048 f32 via global_load_lds, pre-swizzled src ----
    // chunk i = row i (8 KB); wave w covers 16B-units [w*64, w*64+64).
    // phys unit (w*64+lane) receives logical unit (w*64 + (lane^(i&7))).
#pragma unroll
    for (int i = 0; i < 16; ++i) {
        const int u = w * 64 + (l ^ (i & 7));    // logical 16B unit (f32 idx u*4)
        const float* src = (w < 4)
            ? (q + (size_t)(r0 + i) * DD + u * 4)
            : (x + (size_t)(r0 + i) * DD + (u * 4 - DD));
        __builtin_amdgcn_global_load_lds((GC*)src, (LC*)&As[i][w * 256], 16, 0, 0);
    }
    __syncthreads();   // drains the DMA queue = the A stream itself

    // ---- barrier-free K-loop: 64 bodies of K=32 ----
    const int key = lr & 7;
    const float* arow = &As[lr][0];
    const short* pB  = w1p + (size_t)w * 512 + (size_t)l * 8;  // group (c*8+w), lane l

    auto pack8 = [](const f32x4& f0, const f32x4& f1) -> bf16x8 {
        bf16x8 s;
        s[0] = f2bf(f0[0]); s[1] = f2bf(f0[1]); s[2] = f2bf(f0[2]); s[3] = f2bf(f0[3]);
        s[4] = f2bf(f1[0]); s[5] = f2bf(f1[1]); s[6] = f2bf(f1[2]); s[7] = f2bf(f1[3]);
        return s;
    };

    f32x4 acc = (f32x4)0.f;
    bf16x8 BA0, BA1, BA2, BA3, BB0, BB1, BB2, BB3;

#define LOADB4(c4, e0, e1, e2, e3)                                   \
    { const short* s_ = pB + (size_t)(c4) * 4 * 4096;                \
      e0 = *(const bf16x8*)s_;                                       \
      e1 = *(const bf16x8*)(s_ + 4096);                              \
      e2 = *(const bf16x8*)(s_ + 8192);                              \
      e3 = *(const bf16x8*)(s_ + 12288); }

#define BODY(c, bfrag)                                               \
    { const int ku = (c) * 8 + lg * 2;                               \
      f32x4 f0 = *(const f32x4*)(arow + ((ku ^ key) << 2));          \
      f32x4 f1 = *(const f32x4*)(arow + (((ku + 1) ^ key) << 2));    \
      bf16x8 a_ = pack8(f0, f1);                                     \
      acc = __builtin_amdgcn_mfma_f32_16x16x32_bf16(a_, bfrag, acc, 0, 0, 0); }

    LOADB4(0, BA0, BA1, BA2, BA3);
#pragma unroll 1
    for (int g = 0; g < 16; g += 2) {
        LOADB4(g + 1, BB0, BB1, BB2, BB3);
        { const int c = g * 4;
          BODY(c, BA0); BODY(c + 1, BA1); BODY(c + 2, BA2); BODY(c + 3, BA3); }
        if (g + 2 < 16) { LOADB4(g + 2, BA0, BA1, BA2, BA3); }
        { const int c = g * 4 + 4;
          BODY(c, BB0); BODY(c + 1, BB1); BODY(c + 2, BB2); BODY(c + 3, BB3); }
    }
#undef LOADB4
#undef BODY

    // ---- epilogue: tiles -> hsum, bias+relu+W2, 16-lane reduce, compact ----
#pragma unroll
    for (int r = 0; r < 4; ++r)
        hsum[lg * 4 + r][w * 16 + lr] = acc[r];
    __syncthreads();
    if (t < 256) {
        const int row = t >> 4;
        const int cg  = t & 15;
        const int c0  = cg * 8;
        f32x4 s0 = *(const f32x4*)&hsum[row][c0];
        f32x4 s1 = *(const f32x4*)&hsum[row][c0 + 4];
        float a2 = 0.f;
#pragma unroll
        for (int j = 0; j < 4; ++j) {
            const int ca = c0 + j, cb = c0 + 4 + j;
            const float ba = (ca < HH) ? b1[ca] : 0.f;
            const float wa = (ca < HH) ? W2[ca] : 0.f;
            const float bb = (cb < HH) ? b1[cb] : 0.f;
            const float wb = (cb < HH) ? W2[cb] : 0.f;
            a2 = fmaf(fmaxf(s0[j] + ba, 0.f), wa, a2);
            a2 = fmaf(fmaxf(s1[j] + bb, 0.f), wb, a2);
        }
        a2 += __shfl_xor(a2, 1);
        a2 += __shfl_xor(a2, 2);
        a2 += __shfl_xor(a2, 4);
        a2 += __shfl_xor(a2, 8);
        if (cg == 0) {
            const float sv = a2 + b2[0];
            const int i = r0 + row;
            const int g = bidx[i];
            if (y[i]) {
                int idx = atomicAdd(&cnt1[g], 1);
                if (idx < LCAP) sp[g * LCAP + idx] = sv;
            } else {
                int idx = atomicAdd(&cnt0[g], 1);
                if (idx < LCAP) sn[g * LCAP + idx] = sv;
            }
        }
    }
}

// grid = NB*8 blocks; block (g, sl) handles pos indices p ≡ sl (mod 8).
__global__ __launch_bounds__(256) void pairsum_kernel(
    const float* __restrict__ sp, const float* __restrict__ sn,
    const int* __restrict__ cnt1, const int* __restrict__ cnt0,
    float* __restrict__ partial)
{
    __shared__ float lsn[LCAP];
    __shared__ float lsp[64];
    __shared__ float wsum[4];
    const int g  = blockIdx.x >> 3;
    const int sl = blockIdx.x & 7;
    const int t  = threadIdx.x;
    const int n1 = min(cnt1[g], LCAP);
    const int n0 = min(cnt0[g], LCAP);
    for (int j = t; j < n0; j += 256) lsn[j] = sn[g * LCAP + j];
    const int np = (n1 > sl) ? ((n1 - sl + 7) >> 3) : 0;
    for (int j = t; j < np; j += 256) lsp[j] = sp[g * LCAP + sl + j * 8];
    __syncthreads();
    float acc = 0.f;
    const int total = np * n0;
    for (int u = t; u < total; u += 256) {
        const int ip = u / n0;
        const int j  = u - ip * n0;
        const float d  = lsn[j] - lsp[ip];          // s_neg - s_pos
        const float ad = fabsf(d);
        const float z  = __builtin_exp2f(-ad * 1.44269504f);
        acc += fmaxf(d, 0.f) + __builtin_log2f(1.f + z) * 0.69314718f;
    }
#pragma unroll
    for (int off = 32; off > 0; off >>= 1) acc += __shfl_xor(acc, off, 64);
    const int wid = t >> 6, lane = t & 63;
    if (lane == 0) wsum[wid] = acc;
    __syncthreads();
    if (t == 0) partial[blockIdx.x] = wsum[0] + wsum[1] + wsum[2] + wsum[3];
}

__global__ __launch_bounds__(256) void finalize_kernel(
    const float* __restrict__ partial,
    const int* __restrict__ cnt1, const int* __restrict__ cnt0,
    float* __restrict__ out)
{
    __shared__ float ws_[4], wc_[4];
    const int t = threadIdx.x;
    float sv = partial[t];   // 256 entries
    float cv = 0.f;
    if (t < NB) cv = (float)min(cnt1[t], LCAP) * (float)min(cnt0[t], LCAP);
#pragma unroll
    for (int off = 32; off > 0; off >>= 1) {
        sv += __shfl_xor(sv, off, 64);
        cv += __shfl_xor(cv, off, 64);
    }
    const int wid = t >> 6, lane = t & 63;
    if (lane == 0) { ws_[wid] = sv; wc_[wid] = cv; }
    __syncthreads();
    if (t == 0)
        out[0] = (ws_[0] + ws_[1] + ws_[2] + ws_[3]) /
                 (wc_[0] + wc_[1] + wc_[2] + wc_[3]);
}

extern "C" void kernel_launch(void* const* d_in, const int* in_sizes, int n_in,
                              void* d_out, int out_size, void* d_ws, size_t ws_size,
                              hipStream_t stream)
{
    const int*   b  = (const int*)d_in[0];
    const float* q  = (const float*)d_in[1];
    const float* x  = (const float*)d_in[2];
    const int*   y  = (const int*)d_in[3];
    const float* W1 = (const float*)d_in[4];
    const float* b1 = (const float*)d_in[5];
    const float* W2 = (const float*)d_in[6];
    const float* b2 = (const float*)d_in[7];
    float* out = (float*)d_out;

    char* base = (char*)d_ws;
    short* w1p     = (short*)base;                          // 512 KB packed B
    float* sp      = (float*)(base + 524288);               // 64 KB
    float* sn      = (float*)(base + 524288 + 65536);       // 64 KB
    int*   cnt1    = (int*)(base + 524288 + 131072);        // 128 B
    int*   cnt0    = cnt1 + NB;                             // 128 B
    float* partial = (float*)(base + 524288 + 131072 + 256);// 1 KB

    prep_w1p<<<KT / 32, 256, 0, stream>>>(W1, w1p, cnt1, cnt0);
    encoder_mfma<<<NN / 16, 512, 0, stream>>>(q, x, w1p, b1, W2, b2,
                                              b, y, sp, sn, cnt1, cnt0);
    pairsum_kernel<<<NB * 8, 256, 0, stream>>>(sp, sn, cnt1, cnt0, partial);
    finalize_kernel<<<1, 256, 0, stream>>>(partial, cnt1, cnt0, out);
}

// Round 16
// 53.304 us; speedup vs baseline: 1.3854x; 1.3854x over previous
//
#include <hip/hip_runtime.h>
#include <math.h>
#include <stdint.h>

#define NN 8192
#define DD 1024
#define KT 2048   // 2*D
#define HH 100
#define HP 128    // padded hidden
#define LCAP 512
#define NB 32
#define NCH 16    // 64-k bodies per K-half
#define COPYE 262144  // elements per w1p copy (512 KB)

typedef short bf16x8 __attribute__((ext_vector_type(8)));
typedef short bf16x4 __attribute__((ext_vector_type(4)));
typedef float f32x4 __attribute__((ext_vector_type(4)));

__device__ __forceinline__ short f2bf(float f) {
    uint32_t u = __builtin_bit_cast(uint32_t, f);
    u += 0x7FFF + ((u >> 16) & 1);   // RTNE
    return (short)(u >> 16);
}

// W1 fp32 [2048][100] -> w1p packed fragments, REPLICATED 8x (one copy per XCD)
// to kill the cross-chip hot-line on B. Block 0 zeroes compaction counters.
__global__ __launch_bounds__(256) void prep_w1p(const float* __restrict__ W1,
                                                short* __restrict__ w1p,
                                                int* __restrict__ cnt1,
                                                int* __restrict__ cnt0)
{
    __shared__ float ld[32][104];
    const int t  = threadIdx.x;
    if (blockIdx.x == 0 && t < 64) {
        if (t < 32) cnt1[t] = 0; else cnt0[t - 32] = 0;
    }
    const int k0 = blockIdx.x * 32;          // 64 blocks
    for (int i = t; i < 32 * HH; i += 256) {
        const int kk = i / HH, cc = i - kk * HH;
        ld[kk][cc] = W1[(size_t)(k0 + kk) * HH + cc];
    }
    __syncthreads();
    for (int idx = t; idx < 512; idx += 256) {
        const int tt = idx >> 6, l = idx & 63;
        const int lr = l & 15, lg = l >> 4;
        const int col = tt * 16 + lr;
        bf16x8 r;
#pragma unroll
        for (int j = 0; j < 8; ++j)
            r[j] = (col < HH) ? f2bf(ld[lg * 8 + j][col]) : (short)0;
        const size_t off = ((size_t)(blockIdx.x * 8 + tt) * 64 + l) * 8;
#pragma unroll
        for (int cp = 0; cp < 8; ++cp)
            *(bf16x8*)(w1p + (size_t)cp * COPYE + off) = r;
    }
}

// R12 structure (verified, conflict-free): 512 thr / 8 waves; 16 rows/block.
// Waves 0-3: K half 0 (q); waves 4-7: half 1 (x). Whole K-half A staged to LDS
// once (1 barrier), then barrier-free K-loop.
// NEW: per-XCD B copy (hw&7) + per-block rotated body order ((hw>>3)&15) to
// decorrelate B requests across blocks.
__global__ __launch_bounds__(512) void encoder_mfma(
    const float* __restrict__ q, const float* __restrict__ x,
    const short* __restrict__ w1p,
    const float* __restrict__ b1, const float* __restrict__ W2,
    const float* __restrict__ b2,
    const int* __restrict__ bidx, const int* __restrict__ y,
    float* __restrict__ sp, float* __restrict__ sn,
    int* __restrict__ cnt1, int* __restrict__ cnt0)
{
    __shared__ short As[2][16][NCH][64];  // 64 KB: [half][row][body][64k], swizzled 8B slots
    __shared__ float hsum[16][HP + 4];
    __shared__ float fold[4][16];
    const int t    = threadIdx.x;
    const int w    = t >> 6;             // 0..7
    const int half = w >> 2;             // K half
    const int wc   = w & 3;              // col wave
    const int l    = t & 63;
    const int lr   = l & 15;
    const int lg   = l >> 4;
    const int hw   = blockIdx.x;
    const int r0   = hw * 16;
    const int rot  = (hw >> 3) & 15;     // body rotation (XCD-mates spread)

    // ---- stage entire K-half: 16 coalesced float4 loads/thread, 2 batches ----
    const int ts    = t & 255;
    const int srow  = ts >> 4;
    const int sslot = ts & 15;
    const int wslot = (sslot ^ srow) * 4;
    const float* abase = (half ? x : q) + (size_t)(r0 + srow) * DD + sslot * 4;
    auto cvt4 = [&](const float4& v) {
        bf16x4 s;
        s[0] = f2bf(v.x); s[1] = f2bf(v.y); s[2] = f2bf(v.z); s[3] = f2bf(v.w);
        return s;
    };
    {
        float4 g[8];
#pragma unroll
        for (int p = 0; p < 8; ++p) g[p] = *(const float4*)(abase + p * 64);
#pragma unroll
        for (int p = 0; p < 8; ++p)
            *(bf16x4*)&As[half][srow][p][wslot] = cvt4(g[p]);
#pragma unroll
        for (int p = 0; p < 8; ++p) g[p] = *(const float4*)(abase + (p + 8) * 64);
#pragma unroll
        for (int p = 0; p < 8; ++p)
            *(bf16x4*)&As[half][srow][p + 8][wslot] = cvt4(g[p]);
    }
    __syncthreads();   // the ONLY barrier before the epilogue

    // ---- barrier-free K-loop (rotated body order) ----
    const int p0 = ((2 * lg)     ^ lr) * 4;
    const int p1 = ((2 * lg + 1) ^ lr) * 4;
    const int p2 = ((2 * lg + 8) ^ lr) * 4;
    const int p3 = ((2 * lg + 9) ^ lr) * 4;

    const short* pB = w1p + (size_t)(hw & 7) * COPYE
                    + (size_t)half * NCH * 8192
                    + ((size_t)(2 * wc) * 64 + l) * 8;
#define LOADB(c, x0, x1, x2, x3)                           \
    { const size_t e_ = (size_t)(c) * 8192;                \
      x0 = *(const bf16x8*)(pB + e_);                      \
      x1 = *(const bf16x8*)(pB + e_ + 4096);               \
      x2 = *(const bf16x8*)(pB + e_ + 512);                \
      x3 = *(const bf16x8*)(pB + e_ + 4096 + 512); }

    f32x4 acc0 = (f32x4)0.f, acc1 = (f32x4)0.f;
    bf16x8 bA0, bA1, bA2, bA3, bB0, bB1, bB2, bB3;

#define FRAGS_MFMA(c, b0, b1_, b2_, b3_)                                    \
    { const short* ar = &As[half][lr][c][0];                                \
      bf16x4 g0 = *(const bf16x4*)(ar + p0);                                \
      bf16x4 g1 = *(const bf16x4*)(ar + p1);                                \
      bf16x4 g2 = *(const bf16x4*)(ar + p2);                                \
      bf16x4 g3 = *(const bf16x4*)(ar + p3);                                \
      bf16x8 aa0 = __builtin_shufflevector(g0, g1, 0,1,2,3,4,5,6,7);        \
      bf16x8 aa1 = __builtin_shufflevector(g2, g3, 0,1,2,3,4,5,6,7);        \
      acc0 = __builtin_amdgcn_mfma_f32_16x16x32_bf16(aa0, b0,  acc0, 0,0,0);\
      acc0 = __builtin_amdgcn_mfma_f32_16x16x32_bf16(aa1, b1_, acc0, 0,0,0);\
      acc1 = __builtin_amdgcn_mfma_f32_16x16x32_bf16(aa0, b2_, acc1, 0,0,0);\
      acc1 = __builtin_amdgcn_mfma_f32_16x16x32_bf16(aa1, b3_, acc1, 0,0,0); }

    int c = rot;
    LOADB(c, bA0, bA1, bA2, bA3);
#pragma unroll 1
    for (int j = 0; j < NCH; j += 2) {
        const int c1 = (c + 1) & 15;
        const int c2 = (c + 2) & 15;
        LOADB(c1, bB0, bB1, bB2, bB3);
        FRAGS_MFMA(c, bA0, bA1, bA2, bA3);
        LOADB(c2, bA0, bA1, bA2, bA3);
        FRAGS_MFMA(c1, bB0, bB1, bB2, bB3);
        c = c2;
    }

    // ---- epilogue: cross-half pre-activation sum, relu+W2, fold, compact ----
    if (half == 0) {
#pragma unroll
        for (int r = 0; r < 4; ++r) {
            hsum[lg * 4 + r][wc * 32 + lr]      = acc0[r];
            hsum[lg * 4 + r][wc * 32 + lr + 16] = acc1[r];
        }
    }
    __syncthreads();
    if (half == 1) {
#pragma unroll
        for (int r = 0; r < 4; ++r) {
            hsum[lg * 4 + r][wc * 32 + lr]      += acc0[r];
            hsum[lg * 4 + r][wc * 32 + lr + 16] += acc1[r];
        }
    }
    __syncthreads();
    if (half == 0) {
        const int c0 = wc * 32 + lr;
        const int c1 = c0 + 16;
        const float bb0 = (c0 < HH) ? b1[c0] : 0.f;
        const float ww0 = (c0 < HH) ? W2[c0] : 0.f;
        const float bb1 = (c1 < HH) ? b1[c1] : 0.f;
        const float ww1 = (c1 < HH) ? W2[c1] : 0.f;
#pragma unroll
        for (int r = 0; r < 4; ++r) {
            const int row = lg * 4 + r;
            float v = fmaf(fmaxf(hsum[row][c0] + bb0, 0.f), ww0,
                           fmaxf(hsum[row][c1] + bb1, 0.f) * ww1);
            v += __shfl_xor(v, 1);
            v += __shfl_xor(v, 2);
            v += __shfl_xor(v, 4);
            v += __shfl_xor(v, 8);
            if (lr == 0) fold[wc][row] = v;
        }
    }
    __syncthreads();
    if (t < 16) {
        const float sv = fold[0][t] + fold[1][t] + fold[2][t] + fold[3][t] + b2[0];
        const int i = r0 + t;
        const int g = bidx[i];
        if (y[i]) {
            int idx = atomicAdd(&cnt1[g], 1);
            if (idx < LCAP) sp[g * LCAP + idx] = sv;
        } else {
            int idx = atomicAdd(&cnt0[g], 1);
            if (idx < LCAP) sn[g * LCAP + idx] = sv;
        }
    }
#undef LOADB
#undef FRAGS_MFMA
}

// grid = NB*8 blocks; block (g, sl) handles pos indices p ≡ sl (mod 8).
__global__ __launch_bounds__(256) void pairsum_kernel(
    const float* __restrict__ sp, const float* __restrict__ sn,
    const int* __restrict__ cnt1, const int* __restrict__ cnt0,
    float* __restrict__ partial)
{
    __shared__ float lsn[LCAP];
    __shared__ float lsp[64];
    __shared__ float wsum[4];
    const int g  = blockIdx.x >> 3;
    const int sl = blockIdx.x & 7;
    const int t  = threadIdx.x;
    const int n1 = min(cnt1[g], LCAP);
    const int n0 = min(cnt0[g], LCAP);
    for (int j = t; j < n0; j += 256) lsn[j] = sn[g * LCAP + j];
    const int np = (n1 > sl) ? ((n1 - sl + 7) >> 3) : 0;
    for (int j = t; j < np; j += 256) lsp[j] = sp[g * LCAP + sl + j * 8];
    __syncthreads();
    float acc = 0.f;
    const int total = np * n0;
    for (int u = t; u < total; u += 256) {
        const int ip = u / n0;
        const int j  = u - ip * n0;
        const float d  = lsn[j] - lsp[ip];          // s_neg - s_pos
        const float ad = fabsf(d);
        const float z  = __builtin_exp2f(-ad * 1.44269504f);
        acc += fmaxf(d, 0.f) + __builtin_log2f(1.f + z) * 0.69314718f;
    }
#pragma unroll
    for (int off = 32; off > 0; off >>= 1) acc += __shfl_xor(acc, off, 64);
    const int wid = t >> 6, lane = t & 63;
    if (lane == 0) wsum[wid] = acc;
    __syncthreads();
    if (t == 0) partial[blockIdx.x] = wsum[0] + wsum[1] + wsum[2] + wsum[3];
}

__global__ __launch_bounds__(256) void finalize_kernel(
    const float* __restrict__ partial,
    const int* __restrict__ cnt1, const int* __restrict__ cnt0,
    float* __restrict__ out)
{
    __shared__ float ws_[4], wc_[4];
    const int t = threadIdx.x;
    float sv = partial[t];   // 256 entries
    float cv = 0.f;
    if (t < NB) cv = (float)min(cnt1[t], LCAP) * (float)min(cnt0[t], LCAP);
#pragma unroll
    for (int off = 32; off > 0; off >>= 1) {
        sv += __shfl_xor(sv, off, 64);
        cv += __shfl_xor(cv, off, 64);
    }
    const int wid = t >> 6, lane = t & 63;
    if (lane == 0) { ws_[wid] = sv; wc_[wid] = cv; }
    __syncthreads();
    if (t == 0)
        out[0] = (ws_[0] + ws_[1] + ws_[2] + ws_[3]) /
                 (wc_[0] + wc_[1] + wc_[2] + wc_[3]);
}

extern "C" void kernel_launch(void* const* d_in, const int* in_sizes, int n_in,
                              void* d_out, int out_size, void* d_ws, size_t ws_size,
                              hipStream_t stream)
{
    const int*   b  = (const int*)d_in[0];
    const float* q  = (const float*)d_in[1];
    const float* x  = (const float*)d_in[2];
    const int*   y  = (const int*)d_in[3];
    const float* W1 = (const float*)d_in[4];
    const float* b1 = (const float*)d_in[5];
    const float* W2 = (const float*)d_in[6];
    const float* b2 = (const float*)d_in[7];
    float* out = (float*)d_out;

    char* base = (char*)d_ws;
    short* w1p     = (short*)base;                            // 8 x 512 KB replicated B
    float* sp      = (float*)(base + 4194304);                // 64 KB
    float* sn      = (float*)(base + 4194304 + 65536);        // 64 KB
    int*   cnt1    = (int*)(base + 4194304 + 131072);         // 128 B
    int*   cnt0    = cnt1 + NB;                               // 128 B
    float* partial = (float*)(base + 4194304 + 131072 + 256); // 1 KB

    prep_w1p<<<KT / 32, 256, 0, stream>>>(W1, w1p, cnt1, cnt0);
    encoder_mfma<<<NN / 16, 512, 0, stream>>>(q, x, w1p, b1, W2, b2,
                                              b, y, sp, sn, cnt1, cnt0);
    pairsum_kernel<<<NB * 8, 256, 0, stream>>>(sp, sn, cnt1, cnt0, partial);
    finalize_kernel<<<1, 256, 0, stream>>>(partial, cnt1, cnt0, out);
}

// Round 18
// 51.088 us; speedup vs baseline: 1.4455x; 1.0434x over previous
//
#include <hip/hip_runtime.h>
#include <math.h>
#include <stdint.h>

#define NN 8192
#define DD 1024
#define KT 2048   // 2*D
#define HH 100
#define HP 128    // padded hidden
#define LCAP 512
#define NB 32
#define NCH 16    // 64-k bodies per K-half

typedef short bf16x8 __attribute__((ext_vector_type(8)));
typedef short bf16x4 __attribute__((ext_vector_type(4)));
typedef float f32x4 __attribute__((ext_vector_type(4)));

__device__ __forceinline__ short f2bf(float f) {
    uint32_t u = __builtin_bit_cast(uint32_t, f);
    u += 0x7FFF + ((u >> 16) & 1);   // RTNE
    return (short)(u >> 16);
}

// W1 fp32 [2048][100] -> w1p packed fragments (verified R9-R16).
// Block 0 zeroes compaction counters.
__global__ __launch_bounds__(256) void prep_w1p(const float* __restrict__ W1,
                                                short* __restrict__ w1p,
                                                int* __restrict__ cnt1,
                                                int* __restrict__ cnt0)
{
    __shared__ float ld[32][104];
    const int t  = threadIdx.x;
    if (blockIdx.x == 0 && t < 64) {
        if (t < 32) cnt1[t] = 0; else cnt0[t - 32] = 0;
    }
    const int k0 = blockIdx.x * 32;          // 64 blocks
    for (int i = t; i < 32 * HH; i += 256) {
        const int kk = i / HH, cc = i - kk * HH;
        ld[kk][cc] = W1[(size_t)(k0 + kk) * HH + cc];
    }
    __syncthreads();
    for (int idx = t; idx < 512; idx += 256) {
        const int tt = idx >> 6, l = idx & 63;
        const int lr = l & 15, lg = l >> 4;
        const int col = tt * 16 + lr;
        bf16x8 r;
#pragma unroll
        for (int j = 0; j < 8; ++j)
            r[j] = (col < HH) ? f2bf(ld[lg * 8 + j][col]) : (short)0;
        *(bf16x8*)(w1p + ((size_t)(blockIdx.x * 8 + tt) * 64 + l) * 8) = r;
    }
}

// R12 structure (verified 43 µs encoder): 512 thr / 8 waves; 16 rows/block.
// Waves 0-3: K half 0 (q); waves 4-7: half 1 (x). Whole K-half A staged to LDS
// once (1 barrier), then barrier-free K-loop.
// R17 change (single variable): B prefetch restructured to 4-body groups with
// 2 groups in flight -> prefetch distance = 4 FRAGS (~400-800 cy) instead of 1.
__global__ __launch_bounds__(512) void encoder_mfma(
    const float* __restrict__ q, const float* __restrict__ x,
    const short* __restrict__ w1p,
    const float* __restrict__ b1, const float* __restrict__ W2,
    const float* __restrict__ b2,
    const int* __restrict__ bidx, const int* __restrict__ y,
    float* __restrict__ sp, float* __restrict__ sn,
    int* __restrict__ cnt1, int* __restrict__ cnt0)
{
    __shared__ short As[2][16][NCH][64];  // 64 KB, swizzled 8B slots
    __shared__ float hsum[16][HP + 4];
    __shared__ float fold[4][16];
    const int t    = threadIdx.x;
    const int w    = t >> 6;             // 0..7
    const int half = w >> 2;             // K half
    const int wc   = w & 3;              // col wave
    const int l    = t & 63;
    const int lr   = l & 15;
    const int lg   = l >> 4;
    const int r0   = blockIdx.x * 16;

    // ---- stage entire K-half (identical to R12) ----
    const int ts    = t & 255;
    const int srow  = ts >> 4;
    const int sslot = ts & 15;
    const int wslot = (sslot ^ srow) * 4;
    const float* abase = (half ? x : q) + (size_t)(r0 + srow) * DD + sslot * 4;
    auto cvt4 = [&](const float4& v) {
        bf16x4 s;
        s[0] = f2bf(v.x); s[1] = f2bf(v.y); s[2] = f2bf(v.z); s[3] = f2bf(v.w);
        return s;
    };
    {
        float4 g[8];
#pragma unroll
        for (int p = 0; p < 8; ++p) g[p] = *(const float4*)(abase + p * 64);
#pragma unroll
        for (int p = 0; p < 8; ++p)
            *(bf16x4*)&As[half][srow][p][wslot] = cvt4(g[p]);
#pragma unroll
        for (int p = 0; p < 8; ++p) g[p] = *(const float4*)(abase + (p + 8) * 64);
#pragma unroll
        for (int p = 0; p < 8; ++p)
            *(bf16x4*)&As[half][srow][p + 8][wslot] = cvt4(g[p]);
    }
    __syncthreads();   // the ONLY barrier before the epilogue

    // ---- barrier-free K-loop, deep-grouped B prefetch ----
    const int p0 = ((2 * lg)     ^ lr) * 4;
    const int p1 = ((2 * lg + 1) ^ lr) * 4;
    const int p2 = ((2 * lg + 8) ^ lr) * 4;
    const int p3 = ((2 * lg + 9) ^ lr) * 4;

    const short* pB = w1p + (size_t)half * NCH * 8192
                    + ((size_t)(2 * wc) * 64 + l) * 8;

    f32x4 acc0 = (f32x4)0.f, acc1 = (f32x4)0.f;

#define LB1(c, e0, e1, e2, e3)                             \
    { const short* s_ = pB + (size_t)(c) * 8192;           \
      e0 = *(const bf16x8*)s_;                             \
      e1 = *(const bf16x8*)(s_ + 4096);                    \
      e2 = *(const bf16x8*)(s_ + 512);                     \
      e3 = *(const bf16x8*)(s_ + 4096 + 512); }

#define FR1(c, e0, e1, e2, e3)                                              \
    { const short* ar = &As[half][lr][c][0];                                \
      bf16x4 g0 = *(const bf16x4*)(ar + p0);                                \
      bf16x4 g1 = *(const bf16x4*)(ar + p1);                                \
      bf16x4 g2 = *(const bf16x4*)(ar + p2);                                \
      bf16x4 g3 = *(const bf16x4*)(ar + p3);                                \
      bf16x8 aa0 = __builtin_shufflevector(g0, g1, 0,1,2,3,4,5,6,7);        \
      bf16x8 aa1 = __builtin_shufflevector(g2, g3, 0,1,2,3,4,5,6,7);        \
      acc0 = __builtin_amdgcn_mfma_f32_16x16x32_bf16(aa0, e0, acc0, 0,0,0); \
      acc0 = __builtin_amdgcn_mfma_f32_16x16x32_bf16(aa1, e1, acc0, 0,0,0); \
      acc1 = __builtin_amdgcn_mfma_f32_16x16x32_bf16(aa0, e2, acc1, 0,0,0); \
      acc1 = __builtin_amdgcn_mfma_f32_16x16x32_bf16(aa1, e3, acc1, 0,0,0); }

    bf16x8 A00,A01,A02,A03, A10,A11,A12,A13, A20,A21,A22,A23, A30,A31,A32,A33;
    bf16x8 B00,B01,B02,B03, B10,B11,B12,B13, B20,B21,B22,B23, B30,B31,B32,B33;

    // prologue: group 0 (bodies 0-3) into GA
    LB1(0, A00,A01,A02,A03) LB1(1, A10,A11,A12,A13)
    LB1(2, A20,A21,A22,A23) LB1(3, A30,A31,A32,A33)
    // iter 0: load group 1 into GB, compute group 0
    LB1(4, B00,B01,B02,B03) LB1(5, B10,B11,B12,B13)
    LB1(6, B20,B21,B22,B23) LB1(7, B30,B31,B32,B33)
    FR1(0, A00,A01,A02,A03) FR1(1, A10,A11,A12,A13)
    FR1(2, A20,A21,A22,A23) FR1(3, A30,A31,A32,A33)
    // iter 1: load group 2 into GA, compute group 1
    LB1(8,  A00,A01,A02,A03) LB1(9,  A10,A11,A12,A13)
    LB1(10, A20,A21,A22,A23) LB1(11, A30,A31,A32,A33)
    FR1(4, B00,B01,B02,B03) FR1(5, B10,B11,B12,B13)
    FR1(6, B20,B21,B22,B23) FR1(7, B30,B31,B32,B33)
    // iter 2: load group 3 into GB, compute group 2
    LB1(12, B00,B01,B02,B03) LB1(13, B10,B11,B12,B13)
    LB1(14, B20,B21,B22,B23) LB1(15, B30,B31,B32,B33)
    FR1(8,  A00,A01,A02,A03) FR1(9,  A10,A11,A12,A13)
    FR1(10, A20,A21,A22,A23) FR1(11, A30,A31,A32,A33)
    // iter 3: compute group 3
    FR1(12, B00,B01,B02,B03) FR1(13, B10,B11,B12,B13)
    FR1(14, B20,B21,B22,B23) FR1(15, B30,B31,B32,B33)
#undef LB1
#undef FR1

    // ---- epilogue (identical to R12) ----
    if (half == 0) {
#pragma unroll
        for (int r = 0; r < 4; ++r) {
            hsum[lg * 4 + r][wc * 32 + lr]      = acc0[r];
            hsum[lg * 4 + r][wc * 32 + lr + 16] = acc1[r];
        }
    }
    __syncthreads();
    if (half == 1) {
#pragma unroll
        for (int r = 0; r < 4; ++r) {
            hsum[lg * 4 + r][wc * 32 + lr]      += acc0[r];
            hsum[lg * 4 + r][wc * 32 + lr + 16] += acc1[r];
        }
    }
    __syncthreads();
    if (half == 0) {
        const int c0 = wc * 32 + lr;
        const int c1 = c0 + 16;
        const float bb0 = (c0 < HH) ? b1[c0] : 0.f;
        const float ww0 = (c0 < HH) ? W2[c0] : 0.f;
        const float bb1 = (c1 < HH) ? b1[c1] : 0.f;
        const float ww1 = (c1 < HH) ? W2[c1] : 0.f;
#pragma unroll
        for (int r = 0; r < 4; ++r) {
            const int row = lg * 4 + r;
            float v = fmaf(fmaxf(hsum[row][c0] + bb0, 0.f), ww0,
                           fmaxf(hsum[row][c1] + bb1, 0.f) * ww1);
            v += __shfl_xor(v, 1);
            v += __shfl_xor(v, 2);
            v += __shfl_xor(v, 4);
            v += __shfl_xor(v, 8);
            if (lr == 0) fold[wc][row] = v;
        }
    }
    __syncthreads();
    if (t < 16) {
        const float sv = fold[0][t] + fold[1][t] + fold[2][t] + fold[3][t] + b2[0];
        const int i = r0 + t;
        const int g = bidx[i];
        if (y[i]) {
            int idx = atomicAdd(&cnt1[g], 1);
            if (idx < LCAP) sp[g * LCAP + idx] = sv;
        } else {
            int idx = atomicAdd(&cnt0[g], 1);
            if (idx < LCAP) sn[g * LCAP + idx] = sv;
        }
    }
}

// grid = NB*8 blocks; block (g, sl) handles pos indices p ≡ sl (mod 8).
__global__ __launch_bounds__(256) void pairsum_kernel(
    const float* __restrict__ sp, const float* __restrict__ sn,
    const int* __restrict__ cnt1, const int* __restrict__ cnt0,
    float* __restrict__ partial)
{
    __shared__ float lsn[LCAP];
    __shared__ float lsp[64];
    __shared__ float wsum[4];
    const int g  = blockIdx.x >> 3;
    const int sl = blockIdx.x & 7;
    const int t  = threadIdx.x;
    const int n1 = min(cnt1[g], LCAP);
    const int n0 = min(cnt0[g], LCAP);
    for (int j = t; j < n0; j += 256) lsn[j] = sn[g * LCAP + j];
    const int np = (n1 > sl) ? ((n1 - sl + 7) >> 3) : 0;
    for (int j = t; j < np; j += 256) lsp[j] = sp[g * LCAP + sl + j * 8];
    __syncthreads();
    float acc = 0.f;
    const int total = np * n0;
    for (int u = t; u < total; u += 256) {
        const int ip = u / n0;
        const int j  = u - ip * n0;
        const float d  = lsn[j] - lsp[ip];          // s_neg - s_pos
        const float ad = fabsf(d);
        const float z  = __builtin_exp2f(-ad * 1.44269504f);
        acc += fmaxf(d, 0.f) + __builtin_log2f(1.f + z) * 0.69314718f;
    }
#pragma unroll
    for (int off = 32; off > 0; off >>= 1) acc += __shfl_xor(acc, off, 64);
    const int wid = t >> 6, lane = t & 63;
    if (lane == 0) wsum[wid] = acc;
    __syncthreads();
    if (t == 0) partial[blockIdx.x] = wsum[0] + wsum[1] + wsum[2] + wsum[3];
}

__global__ __launch_bounds__(256) void finalize_kernel(
    const float* __restrict__ partial,
    const int* __restrict__ cnt1, const int* __restrict__ cnt0,
    float* __restrict__ out)
{
    __shared__ float ws_[4], wc_[4];
    const int t = threadIdx.x;
    float sv = partial[t];   // 256 entries
    float cv = 0.f;
    if (t < NB) cv = (float)min(cnt1[t], LCAP) * (float)min(cnt0[t], LCAP);
#pragma unroll
    for (int off = 32; off > 0; off >>= 1) {
        sv += __shfl_xor(sv, off, 64);
        cv += __shfl_xor(cv, off, 64);
    }
    const int wid = t >> 6, lane = t & 63;
    if (lane == 0) { ws_[wid] = sv; wc_[wid] = cv; }
    __syncthreads();
    if (t == 0)
        out[0] = (ws_[0] + ws_[1] + ws_[2] + ws_[3]) /
                 (wc_[0] + wc_[1] + wc_[2] + wc_[3]);
}

extern "C" void kernel_launch(void* const* d_in, const int* in_sizes, int n_in,
                              void* d_out, int out_size, void* d_ws, size_t ws_size,
                              hipStream_t stream)
{
    const int*   b  = (const int*)d_in[0];
    const float* q  = (const float*)d_in[1];
    const float* x  = (const float*)d_in[2];
    const int*   y  = (const int*)d_in[3];
    const float* W1 = (const float*)d_in[4];
    const float* b1 = (const float*)d_in[5];
    const float* W2 = (const float*)d_in[6];
    const float* b2 = (const float*)d_in[7];
    float* out = (float*)d_out;

    char* base = (char*)d_ws;
    short* w1p     = (short*)base;                          // 512 KB packed B
    float* sp      = (float*)(base + 524288);               // 64 KB
    float* sn      = (float*)(base + 524288 + 65536);       // 64 KB
    int*   cnt1    = (int*)(base + 524288 + 131072);        // 128 B
    int*   cnt0    = cnt1 + NB;                             // 128 B
    float* partial = (float*)(base + 524288 + 131072 + 256);// 1 KB

    prep_w1p<<<KT / 32, 256, 0, stream>>>(W1, w1p, cnt1, cnt0);
    encoder_mfma<<<NN / 16, 512, 0, stream>>>(q, x, w1p, b1, W2, b2,
                                              b, y, sp, sn, cnt1, cnt0);
    pairsum_kernel<<<NB * 8, 256, 0, stream>>>(sp, sn, cnt1, cnt0, partial);
    finalize_kernel<<<1, 256, 0, stream>>>(partial, cnt1, cnt0, out);
}